// Round 1
// 973.850 us; speedup vs baseline: 1.0226x; 1.0226x over previous
//
#include <hip/hip_runtime.h>

// Bag-level attention selector — wave-per-bag, chunked (4-row) online softmax.
//   repre:        (200000, 690) fp32   <- 552 MB, dominant HBM traffic
//   relation_mat: (53, 690) fp32
//   bias:         (53,) fp32
//   scope:        (25000, 2) int       (contiguous [start,end) per bag)
//   labels:       (200000,) int
//   out:          (25000, 53) fp32
//
// One wave handles one bag. Rows are processed in chunks of 4 with a
// BLOCK-WISE online-softmax update:
//   nm  = max(m, max_i dot_i)
//   acc = acc*exp(m-nm) + sum_i exp(dot_i-nm)*v_i
// This is algebraically identical to the per-row online softmax but:
//   * all 4 rows' loads (48 float2) are issued with zero inter-dependence
//     -> 4x memory-level parallelism to hide ~900cy HBM latency
//   * the 4 shfl-xor dot reductions interleave -> 4x ILP on the serial chain
//   * one acc rescale + one __expf(m-nm) per 4 rows instead of per row
// Phase C unchanged: 8 att vectors in LDS, each rel row read once per block.

#define NBAGS  25000
#define DDIM   690
#define D2     345      // float2 elements per row (rows are 8B-aligned)
#define RREL   53
#define WAVES  8
#define BLOCK  512      // 8 waves
#define CHUNK  4

__global__ __launch_bounds__(BLOCK, 4) void bag_attn_kernel(
    const float* __restrict__ repre,
    const float* __restrict__ rel,
    const float* __restrict__ bias,
    const int*   __restrict__ scope,
    const int*   __restrict__ labels,
    float*       __restrict__ out)
{
    __shared__ float s_att[WAVES * DDIM];   // 22 KB: 8 normalized att vectors

    const int tid  = threadIdx.x;
    const int lane = tid & 63;
    const int wave = tid >> 6;
    const int bag  = blockIdx.x * WAVES + wave;

    const int start = scope[2 * bag];
    const int end   = scope[2 * bag + 1];

    const float2* rel2 = (const float2*)rel;

    // Online-softmax state + lane-strided accumulator (f = lane + 64k, k<6)
    float2 acc[6];
    #pragma unroll
    for (int k = 0; k < 6; ++k) acc[k] = make_float2(0.f, 0.f);
    float m = -3.402823466e38f;
    float l = 0.f;

    for (int row = start; row < end; row += CHUNK) {
        const int nc = end - row;           // rows i < min(nc, CHUNK) active

        // Labels first: all CHUNK loads in flight before anything depends.
        int lab[CHUNK];
        #pragma unroll
        for (int i = 0; i < CHUNK; ++i)
            lab[i] = (i < nc) ? labels[row + i] : 0;

        // Row loads + per-row partial dots. No dependence between rows i:
        // the compiler can keep all 48 float2 global loads outstanding.
        float2 v[CHUNK][6];
        float dot[CHUNK];
        #pragma unroll
        for (int i = 0; i < CHUNK; ++i) {
            if (i < nc) {       // wave-uniform branch (nc uniform per wave)
                const float2* rp = (const float2*)(repre + (size_t)(row + i) * DDIM);
                const float2* rl = rel2 + (size_t)lab[i] * D2;
                float d = 0.f;
                #pragma unroll
                for (int k = 0; k < 6; ++k) {
                    const int f = lane + 64 * k;
                    if (f < D2) {
                        v[i][k] = rp[f];
                        const float2 u = rl[f];
                        d = fmaf(v[i][k].x, u.x, fmaf(v[i][k].y, u.y, d));
                    } else {
                        v[i][k] = make_float2(0.f, 0.f);
                    }
                }
                dot[i] = d;
            } else {
                #pragma unroll
                for (int k = 0; k < 6; ++k) v[i][k] = make_float2(0.f, 0.f);
                dot[i] = -__builtin_inff();  // -inf survives the +-reduce; e=0
            }
        }

        // Interleaved cross-lane reductions: 4 independent shfl chains.
        #pragma unroll
        for (int o = 32; o; o >>= 1) {
            #pragma unroll
            for (int i = 0; i < CHUNK; ++i)
                dot[i] += __shfl_xor(dot[i], o, 64);
        }

        // Block-wise online-softmax update (one rescale per chunk).
        float bm = dot[0];
        #pragma unroll
        for (int i = 1; i < CHUNK; ++i) bm = fmaxf(bm, dot[i]);
        const float nm = fmaxf(m, bm);       // finite: >=1 active row
        const float sc = __expf(m - nm);     // first chunk: exp(-huge)=0

        float e[CHUNK];
        float es = 0.f;
        #pragma unroll
        for (int i = 0; i < CHUNK; ++i) {
            e[i] = __expf(dot[i] - nm);      // inactive rows: exp(-inf)=0
            es  += e[i];
        }
        l = fmaf(l, sc, es);

        #pragma unroll
        for (int k = 0; k < 6; ++k) {
            float ax = acc[k].x * sc;
            float ay = acc[k].y * sc;
            #pragma unroll
            for (int i = 0; i < CHUNK; ++i) {
                ax = fmaf(e[i], v[i][k].x, ax);
                ay = fmaf(e[i], v[i][k].y, ay);
            }
            acc[k].x = ax;
            acc[k].y = ay;
        }
        m = nm;
    }

    // Normalize and publish att vector to LDS
    const float inv = 1.f / l;
    float2* satt2 = (float2*)(s_att + wave * DDIM);
    #pragma unroll
    for (int k = 0; k < 6; ++k) {
        const int f = lane + 64 * k;
        if (f < D2) satt2[f] = make_float2(acc[k].x * inv, acc[k].y * inv);
    }
    __syncthreads();

    // Phase C: out[bag0+g, r] = dot(att[g], rel[r]) + bias[r]
    // Each rel row loaded once per block, dotted against all 8 att vectors.
    const int bag0 = blockIdx.x * WAVES;
    for (int r = wave; r < RREL; r += WAVES) {
        const float2* rl = rel2 + (size_t)r * D2;
        float2 u[6];
        #pragma unroll
        for (int k = 0; k < 6; ++k) {
            const int f = lane + 64 * k;
            u[k] = (f < D2) ? rl[f] : make_float2(0.f, 0.f);
        }
        const float b = bias[r];
        #pragma unroll
        for (int g = 0; g < WAVES; ++g) {
            const float2* a2 = (const float2*)(s_att + g * DDIM);
            float dot = 0.f;
            #pragma unroll
            for (int k = 0; k < 6; ++k) {
                const int f = lane + 64 * k;
                if (f < D2) {
                    const float2 a = a2[f];
                    dot = fmaf(u[k].x, a.x, fmaf(u[k].y, a.y, dot));
                }
            }
            #pragma unroll
            for (int o = 32; o; o >>= 1) dot += __shfl_xor(dot, o, 64);
            if (lane == 0) out[(size_t)(bag0 + g) * RREL + r] = dot + b;
        }
    }
}

extern "C" void kernel_launch(void* const* d_in, const int* in_sizes, int n_in,
                              void* d_out, int out_size, void* d_ws, size_t ws_size,
                              hipStream_t stream)
{
    const float* repre  = (const float*)d_in[0];
    const float* rel    = (const float*)d_in[1];
    const float* bias   = (const float*)d_in[2];
    const int*   scope  = (const int*)d_in[3];
    const int*   labels = (const int*)d_in[4];
    float*       out    = (float*)d_out;

    const int grid = NBAGS / WAVES;   // 3125, exact
    bag_attn_kernel<<<grid, BLOCK, 0, stream>>>(repre, rel, bias, scope, labels, out);
}

// Round 3
// 854.936 us; speedup vs baseline: 1.1648x; 1.1391x over previous
//
#include <hip/hip_runtime.h>

// Bag-level attention selector — wave-per-bag, BRANCH-FREE chunked (4-row)
// online softmax.  (Resubmission of round-2 kernel: the previous bench died
// with an infra error — "container failed twice" — before running; the
// branch-free-loads hypothesis is still untested.)
//
//   repre:        (200000, 690) fp32   <- 552 MB, dominant HBM traffic
//   relation_mat: (53, 690) fp32
//   bias:         (53,) fp32
//   scope:        (25000, 2) int       (contiguous [start,end) per bag)
//   labels:       (200000,) int
//   out:          (25000, 53) fp32
//
// Round-1 post-mortem: VGPR stayed at 56 -> compiler kept the per-row
// load->wait->consume chain because each row's loads sat behind a runtime
// `if (i < nc)` branch. This version removes ALL branches from the chunk
// body so the 24 repre loads (4 rows x 6 float2) are unconditional and can
// be kept in flight together:
//   * padded rows clamp their index to end-1 (always valid) and are
//     neutralized AFTER the reduce via dot[i] = -inf  => e_i = 0.
//   * repre loads for all 4 rows issue before any rel-gather load.
//   * next chunk's labels prefetched while current loads are in flight.
// Block = 256 (4 bags): less __syncthreads imbalance (max of 4 bag sizes,
// not 8), 6250 blocks for scheduling granularity.

#define NBAGS  25000
#define DDIM   690
#define D2     345      // float2 elements per row (rows are 8B-aligned)
#define RREL   53
#define WAVES  4
#define BLOCK  256      // 4 waves
#define CHUNK  4
#define NEG_INF (-3.402823466e38f)

static __device__ __forceinline__ int imin(int a, int b) { return a < b ? a : b; }

__global__ __launch_bounds__(BLOCK, 4) void bag_attn_kernel(
    const float* __restrict__ repre,
    const float* __restrict__ rel,
    const float* __restrict__ bias,
    const int*   __restrict__ scope,
    const int*   __restrict__ labels,
    float*       __restrict__ out)
{
    __shared__ float s_att[WAVES * DDIM];   // 11 KB: 4 normalized att vectors

    const int tid  = threadIdx.x;
    const int lane = tid & 63;
    const int wave = tid >> 6;
    const int bag  = blockIdx.x * WAVES + wave;

    const int start = scope[2 * bag];
    const int end   = scope[2 * bag + 1];   // every bag has >= 1 row

    const float2* rel2 = (const float2*)rel;

    // Online-softmax state + lane-strided accumulator (f = lane + 64k, k<6)
    float2 acc[6];
    #pragma unroll
    for (int k = 0; k < 6; ++k) acc[k] = make_float2(0.f, 0.f);
    float m = NEG_INF;
    float l = 0.f;

    // Labels for the first chunk (clamped -> always valid addresses).
    int lab[CHUNK];
    #pragma unroll
    for (int i = 0; i < CHUNK; ++i) lab[i] = labels[imin(start + i, end - 1)];

    for (int row = start; row < end; row += CHUNK) {
        const int nc = end - row;            // rows i < nc are real

        int rc[CHUNK];
        #pragma unroll
        for (int i = 0; i < CHUNK; ++i) rc[i] = imin(row + i, end - 1);

        // --- 24 unconditional coalesced repre loads, zero inter-dependence.
        float2 v[CHUNK][6];
        #pragma unroll
        for (int i = 0; i < CHUNK; ++i) {
            const float2* rp = (const float2*)(repre + (size_t)rc[i] * DDIM);
            #pragma unroll
            for (int k = 0; k < 6; ++k) {
                const int f = lane + 64 * k;
                v[i][k] = (f < D2) ? rp[f] : make_float2(0.f, 0.f);
            }
        }

        // Prefetch next chunk's labels while the v-loads are in flight.
        int labn[CHUNK];
        {
            const int nrow = row + CHUNK;
            #pragma unroll
            for (int i = 0; i < CHUNK; ++i)
                labn[i] = labels[imin(nrow + i, end - 1)];
        }

        // --- rel gathers folded into 4 independent dot chains.
        float dot[CHUNK];
        #pragma unroll
        for (int i = 0; i < CHUNK; ++i) {
            const float2* rl = rel2 + (size_t)lab[i] * D2;
            float d = 0.f;
            #pragma unroll
            for (int k = 0; k < 6; ++k) {
                const int f = lane + 64 * k;
                if (f < D2) {
                    const float2 u = rl[f];
                    d = fmaf(v[i][k].x, u.x, fmaf(v[i][k].y, u.y, d));
                }
            }
            dot[i] = d;
        }

        // Interleaved cross-lane reductions: 4 independent shfl chains.
        #pragma unroll
        for (int o = 32; o; o >>= 1) {
            #pragma unroll
            for (int i = 0; i < CHUNK; ++i)
                dot[i] += __shfl_xor(dot[i], o, 64);
        }

        // Neutralize padded rows AFTER the reduce: e_i = exp(-inf) = 0.
        #pragma unroll
        for (int i = 0; i < CHUNK; ++i)
            if (i >= nc) dot[i] = NEG_INF;   // i compile-time, nc runtime -> cndmask

        // Block-wise online-softmax update (one rescale per chunk).
        float bm = dot[0];
        #pragma unroll
        for (int i = 1; i < CHUNK; ++i) bm = fmaxf(bm, dot[i]);
        const float nm = fmaxf(m, bm);       // finite: >= 1 active row
        const float sc = __expf(m - nm);     // first chunk: exp(-huge) = 0

        float e[CHUNK];
        float es = 0.f;
        #pragma unroll
        for (int i = 0; i < CHUNK; ++i) {
            e[i] = __expf(dot[i] - nm);      // padded rows contribute 0
            es  += e[i];
        }
        l = fmaf(l, sc, es);

        #pragma unroll
        for (int k = 0; k < 6; ++k) {
            float ax = acc[k].x * sc;
            float ay = acc[k].y * sc;
            #pragma unroll
            for (int i = 0; i < CHUNK; ++i) {
                ax = fmaf(e[i], v[i][k].x, ax);
                ay = fmaf(e[i], v[i][k].y, ay);
            }
            acc[k].x = ax;
            acc[k].y = ay;
        }
        m = nm;

        #pragma unroll
        for (int i = 0; i < CHUNK; ++i) lab[i] = labn[i];
    }

    // Normalize and publish att vector to LDS
    const float inv = 1.f / l;
    float2* satt2 = (float2*)(s_att + wave * DDIM);
    #pragma unroll
    for (int k = 0; k < 6; ++k) {
        const int f = lane + 64 * k;
        if (f < D2) satt2[f] = make_float2(acc[k].x * inv, acc[k].y * inv);
    }
    __syncthreads();

    // Phase C: out[bag0+g, r] = dot(att[g], rel[r]) + bias[r]
    // Each rel row loaded once per block, dotted against all 4 att vectors.
    const int bag0 = blockIdx.x * WAVES;
    for (int r = wave; r < RREL; r += WAVES) {
        const float2* rl = rel2 + (size_t)r * D2;
        float2 u[6];
        #pragma unroll
        for (int k = 0; k < 6; ++k) {
            const int f = lane + 64 * k;
            u[k] = (f < D2) ? rl[f] : make_float2(0.f, 0.f);
        }
        const float b = bias[r];
        #pragma unroll
        for (int g = 0; g < WAVES; ++g) {
            const float2* a2 = (const float2*)(s_att + g * DDIM);
            float dot = 0.f;
            #pragma unroll
            for (int k = 0; k < 6; ++k) {
                const int f = lane + 64 * k;
                if (f < D2) {
                    const float2 a = a2[f];
                    dot = fmaf(u[k].x, a.x, fmaf(u[k].y, a.y, dot));
                }
            }
            #pragma unroll
            for (int o = 32; o; o >>= 1) dot += __shfl_xor(dot, o, 64);
            if (lane == 0) out[(size_t)(bag0 + g) * RREL + r] = dot + b;
        }
    }
}

extern "C" void kernel_launch(void* const* d_in, const int* in_sizes, int n_in,
                              void* d_out, int out_size, void* d_ws, size_t ws_size,
                              hipStream_t stream)
{
    const float* repre  = (const float*)d_in[0];
    const float* rel    = (const float*)d_in[1];
    const float* bias   = (const float*)d_in[2];
    const int*   scope  = (const int*)d_in[3];
    const int*   labels = (const int*)d_in[4];
    float*       out    = (float*)d_out;

    const int grid = NBAGS / WAVES;   // 6250, exact
    bag_attn_kernel<<<grid, BLOCK, 0, stream>>>(repre, rel, bias, scope, labels, out);
}